// Round 4
// baseline (666.123 us; speedup 1.0000x reference)
//
#include <hip/hip_runtime.h>

// Problem constants
#define B_   32
#define N_   512
#define C_   768
#define H_   12
#define D_   64
#define HID_ 3072
#define BN_  (B_*N_)      // 16384 rows

typedef unsigned short u16;
typedef __attribute__((ext_vector_type(8))) short  short8;   // 8 bf16 (4 VGPRs)
typedef __attribute__((ext_vector_type(4))) float  float4v;  // 4 fp32 acc

__device__ __forceinline__ u16 f32_to_bf16(float f) {
  unsigned u = __builtin_bit_cast(unsigned, f);
  u += 0x7fffu + ((u >> 16) & 1u);   // RNE
  return (u16)(u >> 16);
}

// async global->LDS, 16B per lane; lds base must be wave-uniform, lane i lands at base + i*16B
__device__ __forceinline__ void load_lds16(const u16* g, u16* l) {
  __builtin_amdgcn_global_load_lds(
      (const __attribute__((address_space(1))) unsigned int*)g,
      (__attribute__((address_space(3))) unsigned int*)l,
      16, 0, 0);
}

// ---------------- weight cast f32 -> bf16 ----------------
__global__ void cast_kernel(const float* __restrict__ src, u16* __restrict__ dst, int n) {
  int i = blockIdx.x * 256 + threadIdx.x;
  if (i < n) dst[i] = f32_to_bf16(src[i]);
}

// ---------------- LayerNorm (row = 768 fp32) -> bf16 ----------------
__global__ __launch_bounds__(256)
void ln_kernel(const float* __restrict__ x, const float* __restrict__ w,
               const float* __restrict__ bias, u16* __restrict__ out) {
  const int row = blockIdx.x;
  const int tid = threadIdx.x;
  const float* xr = x + (size_t)row * C_;
  float v0 = xr[tid], v1 = xr[tid + 256], v2 = xr[tid + 512];
  float s = v0 + v1 + v2;
  float q = v0*v0 + v1*v1 + v2*v2;
#pragma unroll
  for (int off = 1; off < 64; off <<= 1) { s += __shfl_xor(s, off); q += __shfl_xor(q, off); }
  __shared__ float red[8];
  int wave = tid >> 6, lane = tid & 63;
  if (lane == 0) { red[wave] = s; red[4 + wave] = q; }
  __syncthreads();
  s = red[0] + red[1] + red[2] + red[3];
  q = red[4] + red[5] + red[6] + red[7];
  float mean = s * (1.0f / C_);
  float var  = q * (1.0f / C_) - mean * mean;
  float rstd = rsqrtf(var + 1e-5f);
  u16* orow = out + (size_t)row * C_;
  orow[tid]       = f32_to_bf16((v0 - mean) * rstd * w[tid]       + bias[tid]);
  orow[tid + 256] = f32_to_bf16((v1 - mean) * rstd * w[tid + 256] + bias[tid + 256]);
  orow[tid + 512] = f32_to_bf16((v2 - mean) * rstd * w[tid + 512] + bias[tid + 512]);
}

// ---------------- 128x128x(BK=64) bf16 NT GEMM: C[M,N] = A[M,K] * W[N,K]^T -------
// LDS layout XOR-swizzled: (row, 16B-group g) lives at row*128B + (g^(row&7))*16B.
// EPI 0: qkv split: cols<1536 -> bf16 unified; cols>=1536 (V) -> Vt[B*H, D, N]
// EPI 1: gelu(y+bias) -> bf16            (FC1)
// EPI 2: 2*(y+bias)   -> fp32            (proj -> x_new)
// EPI 3: y+bias+resid -> fp32            (FC2 -> d_out)
template <int EPI>
__device__ __forceinline__ void gemm_core(const u16* __restrict__ A, const u16* __restrict__ W,
                                          int N, int K,
                                          const float* __restrict__ bias,
                                          const float* __restrict__ resid,
                                          u16* __restrict__ out_bf, float* __restrict__ out_f,
                                          u16* __restrict__ vt_out) {
  __shared__ alignas(16) u16 As[128 * 64];
  __shared__ alignas(16) u16 Ws[128 * 64];
  const int tid  = threadIdx.x;
  const int wave = tid >> 6;
  const int lane = tid & 63;
  const int quad = lane >> 4;
  const int l15  = lane & 15;

  // XCD-aware swizzle: row-major band per XCD for L2 A-strip sharing.
  const int nx    = gridDim.x;
  const int lin   = blockIdx.y * nx + blockIdx.x;
  const int total = nx * gridDim.y;
  const int v     = (lin & 7) * (total >> 3) + (lin >> 3);
  const int m0 = (v / nx) << 7;
  const int n0 = (v % nx) << 7;

  const int wm = (wave >> 1) * 64;
  const int wn = (wave & 1) * 64;

  float4v acc[4][4];
#pragma unroll
  for (int i = 0; i < 4; i++)
#pragma unroll
    for (int j = 0; j < 4; j++) acc[i][j] = (float4v){0.f, 0.f, 0.f, 0.f};

  const int c0   = wave * 4;
  const int srow = lane >> 3;
  const int gcol = ((lane & 7) ^ srow) * 8;
  const u16* Ag[4];
  const u16* Wg[4];
#pragma unroll
  for (int j = 0; j < 4; j++) {
    const int row = (c0 + j) * 8 + srow;
    Ag[j] = A + (size_t)(m0 + row) * K + gcol;
    Wg[j] = W + (size_t)(n0 + row) * K + gcol;
  }

  for (int k0 = 0; k0 < K; k0 += 64) {
    __syncthreads();
#pragma unroll
    for (int j = 0; j < 4; j++) load_lds16(Ag[j] + k0, &As[(c0 + j) * 512]);
#pragma unroll
    for (int j = 0; j < 4; j++) load_lds16(Wg[j] + k0, &Ws[(c0 + j) * 512]);
    __syncthreads();

    short8 af[4][2], bf[4][2];
#pragma unroll
    for (int mi = 0; mi < 4; mi++)
#pragma unroll
      for (int ks = 0; ks < 2; ks++) {
        const int swz = ((ks * 4 + quad) ^ (l15 & 7)) * 8;
        af[mi][ks] = *(const short8*)&As[(wm + mi * 16 + l15) * 64 + swz];
        bf[mi][ks] = *(const short8*)&Ws[(wn + mi * 16 + l15) * 64 + swz];
      }
#pragma unroll
    for (int ks = 0; ks < 2; ks++)
#pragma unroll
      for (int mi = 0; mi < 4; mi++)
#pragma unroll
        for (int ni = 0; ni < 4; ni++)
          acc[mi][ni] = __builtin_amdgcn_mfma_f32_16x16x32_bf16(af[mi][ks], bf[ni][ks], acc[mi][ni], 0, 0, 0);
  }

#pragma unroll
  for (int mi = 0; mi < 4; mi++) {
#pragma unroll
    for (int r = 0; r < 4; r++) {
      const int row = m0 + wm + mi * 16 + quad * 4 + r;   // C/D: row = quad*4+reg (m89)
#pragma unroll
      for (int ni = 0; ni < 4; ni++) {
        const int col = n0 + wn + ni * 16 + l15;          // C/D: col = lane&15
        float v2 = acc[mi][ni][r];
        if (EPI == 0) {
          if (col < 2 * C_) {
            out_bf[(size_t)row * N + col] = f32_to_bf16(v2);
          } else {
            const int voff = col - 2 * C_;
            const int hh = voff >> 6, dd = voff & 63;
            const int bb = row >> 9, nn = row & 511;
            vt_out[((size_t)(bb * H_ + hh) * D_ + dd) * N_ + nn] = f32_to_bf16(v2);
          }
        } else if (EPI == 1) {
          v2 += bias[col];
          v2 = 0.5f * v2 * (1.0f + erff(v2 * 0.70710678118654752f));  // exact GELU
          out_bf[(size_t)row * N + col] = f32_to_bf16(v2);
        } else if (EPI == 2) {
          out_f[(size_t)row * N + col] = 2.0f * (v2 + bias[col]);     // x = o + o quirk
        } else {
          out_f[(size_t)row * N + col] = v2 + bias[col] + resid[(size_t)row * N + col];
        }
      }
    }
  }
}

__global__ __launch_bounds__(256, 3)
void gemm_qkv(const u16* __restrict__ A, const u16* __restrict__ W, int N, int K,
              u16* __restrict__ out_bf, u16* __restrict__ vt_out) {
  gemm_core<0>(A, W, N, K, nullptr, nullptr, out_bf, nullptr, vt_out);
}
__global__ __launch_bounds__(256, 3)
void gemm_proj2x(const u16* __restrict__ A, const u16* __restrict__ W, int N, int K,
                 const float* __restrict__ bias, float* __restrict__ out_f) {
  gemm_core<2>(A, W, N, K, bias, nullptr, nullptr, out_f, nullptr);
}
__global__ __launch_bounds__(256, 3)
void gemm_fc1gelu(const u16* __restrict__ A, const u16* __restrict__ W, int N, int K,
                  const float* __restrict__ bias, u16* __restrict__ out_bf) {
  gemm_core<1>(A, W, N, K, bias, nullptr, out_bf, nullptr, nullptr);
}
__global__ __launch_bounds__(256, 3)
void gemm_fc2res(const u16* __restrict__ A, const u16* __restrict__ W, int N, int K,
                 const float* __restrict__ bias, const float* __restrict__ resid,
                 float* __restrict__ out_f) {
  gemm_core<3>(A, W, N, K, bias, resid, nullptr, out_f, nullptr);
}

// ---------------- flash attention: block = (b, h, 64-query tile) -----------------
// No LDS staging, no barriers. K/V B-fragments load straight from global (L1-hot).
// Only LDS: per-wave P strip (C-layout -> A-layout), XOR-swizzled 8-u16 groups.
__global__ __launch_bounds__(256)
void attn_kernel(const u16* __restrict__ qkv, const u16* __restrict__ vt,
                 u16* __restrict__ o) {
  __shared__ alignas(16) u16 Ps[4][16 * 64];    // per-wave strip [qrow][key], swizzled
  const int tid  = threadIdx.x;
  const int wave = tid >> 6, lane = tid & 63;
  const int quad = lane >> 4, l15 = lane & 15;
  const int qt = blockIdx.x, h = blockIdx.y, b = blockIdx.z;
  const size_t rs3 = 3 * C_;
  u16* myPs = Ps[wave];

  // Q fragments straight from global (A-layout: m=lane&15, k=quad*8+j)
  const int qrow = b * N_ + qt * 64 + wave * 16 + l15;
  const u16* qp = qkv + (size_t)qrow * rs3 + h * D_ + quad * 8;
  const short8 qf0 = *(const short8*)qp;
  const short8 qf1 = *(const short8*)(qp + 32);

  // K: unified layout rows (stride rs3); V: Vt[bh][d][n]
  const u16* kbase = qkv + (size_t)(b * N_) * rs3 + C_ + h * D_ + quad * 8;
  const u16* vbase = vt + (size_t)(b * H_ + h) * D_ * N_ + quad * 8;

  float m[4], l[4];
  float4v oacc[4];
#pragma unroll
  for (int r = 0; r < 4; r++) { m[r] = -1e30f; l[r] = 0.f; }
#pragma unroll
  for (int ni = 0; ni < 4; ni++) oacc[ni] = (float4v){0.f, 0.f, 0.f, 0.f};

  for (int kt = 0; kt < 8; ++kt) {
    // S = Q K^T  (16x64 strip per wave); kf: B[n=key][k=d]
    float4v s[4];
#pragma unroll
    for (int ni = 0; ni < 4; ni++) {
      const u16* kr = kbase + (size_t)(kt * 64 + ni * 16 + l15) * rs3;
      short8 kf0 = *(const short8*)kr;
      short8 kf1 = *(const short8*)(kr + 32);
      s[ni] = (float4v){0.f, 0.f, 0.f, 0.f};
      s[ni] = __builtin_amdgcn_mfma_f32_16x16x32_bf16(qf0, kf0, s[ni], 0, 0, 0);
      s[ni] = __builtin_amdgcn_mfma_f32_16x16x32_bf16(qf1, kf1, s[ni], 0, 0, 0);
    }

    // online softmax (row stats across the 16 l15 lanes of each quad)
    float mt[4];
#pragma unroll
    for (int r = 0; r < 4; r++)
      mt[r] = 0.125f * fmaxf(fmaxf(s[0][r], s[1][r]), fmaxf(s[2][r], s[3][r]));
#pragma unroll
    for (int off = 1; off < 16; off <<= 1)
#pragma unroll
      for (int r = 0; r < 4; r++) mt[r] = fmaxf(mt[r], __shfl_xor(mt[r], off));

    float alpha[4], mnew[4], rsum[4];
#pragma unroll
    for (int r = 0; r < 4; r++) {
      mnew[r] = fmaxf(m[r], mt[r]);
      alpha[r] = __expf(m[r] - mnew[r]);
      rsum[r] = 0.f;
    }
    // write P swizzled: P[row][key] at row*64 + ((key>>3)^(row&7))*8 + (key&7)
#pragma unroll
    for (int ni = 0; ni < 4; ni++)
#pragma unroll
      for (int r = 0; r < 4; r++) {
        float p = __expf(s[ni][r] * 0.125f - mnew[r]);
        rsum[r] += p;
        const int prow = quad * 4 + r;
        const int g = (ni * 2 + (l15 >> 3)) ^ (prow & 7);
        myPs[prow * 64 + g * 8 + (l15 & 7)] = f32_to_bf16(p);
      }
#pragma unroll
    for (int off = 1; off < 16; off <<= 1)
#pragma unroll
      for (int r = 0; r < 4; r++) rsum[r] += __shfl_xor(rsum[r], off);
#pragma unroll
    for (int r = 0; r < 4; r++) { l[r] = l[r] * alpha[r] + rsum[r]; m[r] = mnew[r]; }
#pragma unroll
    for (int ni = 0; ni < 4; ni++)
#pragma unroll
      for (int r = 0; r < 4; r++) oacc[ni][r] *= alpha[r];

    // O += P V  (pf: A[m=q=l15][k=key]; vf: B[n=d][k=key] from Vt, contiguous 16B)
#pragma unroll
    for (int ks = 0; ks < 2; ks++) {
      const int g = (ks * 4 + quad) ^ (l15 & 7);
      short8 pf = *(const short8*)&myPs[l15 * 64 + g * 8];
#pragma unroll
      for (int ni = 0; ni < 4; ni++) {
        const u16* vr = vbase + (size_t)(ni * 16 + l15) * N_ + kt * 64 + ks * 32;
        short8 vf = *(const short8*)vr;
        oacc[ni] = __builtin_amdgcn_mfma_f32_16x16x32_bf16(pf, vf, oacc[ni], 0, 0, 0);
      }
    }
  }

  float inv[4];
#pragma unroll
  for (int r = 0; r < 4; r++) inv[r] = 1.0f / l[r];
#pragma unroll
  for (int ni = 0; ni < 4; ni++)
#pragma unroll
    for (int r = 0; r < 4; r++) {
      int row = b * N_ + qt * 64 + wave * 16 + quad * 4 + r;
      int col = h * D_ + ni * 16 + l15;
      o[(size_t)row * C_ + col] = f32_to_bf16(oacc[ni][r] * inv[r]);
    }
}

// ---------------- launch ----------------
extern "C" void kernel_launch(void* const* d_in, const int* in_sizes, int n_in,
                              void* d_out, int out_size, void* d_ws, size_t ws_size,
                              hipStream_t stream) {
  const float* x      = (const float*)d_in[0];
  const float* ln1_w  = (const float*)d_in[1];
  const float* ln1_b  = (const float*)d_in[2];
  const float* qkv_w  = (const float*)d_in[3];
  const float* proj_w = (const float*)d_in[4];
  const float* proj_b = (const float*)d_in[5];
  const float* ln2_w  = (const float*)d_in[6];
  const float* ln2_b  = (const float*)d_in[7];
  const float* fc1_w  = (const float*)d_in[8];
  const float* fc1_b  = (const float*)d_in[9];
  const float* fc2_w  = (const float*)d_in[10];
  const float* fc2_b  = (const float*)d_in[11];
  float* out = (float*)d_out;

  char* ws = (char*)d_ws;
  size_t off = 0;
  auto alloc = [&](size_t bytes) { void* p = ws + off; off += (bytes + 255) & ~255ull; return p; };
  u16* wqkv  = (u16*)alloc((size_t)3 * C_ * C_ * 2);
  u16* wproj = (u16*)alloc((size_t)C_ * C_ * 2);
  u16* wfc1  = (u16*)alloc((size_t)HID_ * C_ * 2);
  u16* wfc2  = (u16*)alloc((size_t)C_ * HID_ * 2);
  u16* regionA = (u16*)alloc((size_t)BN_ * HID_ * 2);  // h | qkv, later o, later act
  float* xnew  = (float*)alloc((size_t)BN_ * C_ * 4);
  u16* h2      = (u16*)alloc((size_t)BN_ * C_ * 2);

  u16* hbuf = regionA;                        // [BN, C]   (dead after QKV)
  u16* qkvb = regionA + (size_t)BN_ * C_;     // [BN, 3C]  (V cols unused; dead after attn)
  u16* obuf = regionA;                        // [BN, C]   overwrites hbuf
  u16* act  = regionA;                        // [BN, HID] overwrites qkv+o
  u16* vtbuf = (u16*)xnew;                    // [B*H, D, N] aliases xnew (dead before proj writes)

  cast_kernel<<<dim3(3 * C_ * C_ / 256), 256, 0, stream>>>(qkv_w, wqkv, 3 * C_ * C_);
  cast_kernel<<<dim3(C_ * C_ / 256), 256, 0, stream>>>(proj_w, wproj, C_ * C_);
  cast_kernel<<<dim3(HID_ * C_ / 256), 256, 0, stream>>>(fc1_w, wfc1, HID_ * C_);
  cast_kernel<<<dim3(HID_ * C_ / 256), 256, 0, stream>>>(fc2_w, wfc2, C_ * HID_);

  ln_kernel<<<dim3(BN_), 256, 0, stream>>>(x, ln1_w, ln1_b, hbuf);

  gemm_qkv<<<dim3(3 * C_ / 128, BN_ / 128), 256, 0, stream>>>(hbuf, wqkv, 3 * C_, C_, qkvb, vtbuf);

  attn_kernel<<<dim3(N_ / 64, H_, B_), 256, 0, stream>>>(qkvb, vtbuf, obuf);

  gemm_proj2x<<<dim3(C_ / 128, BN_ / 128), 256, 0, stream>>>(obuf, wproj, C_, C_, proj_b, xnew);

  ln_kernel<<<dim3(BN_), 256, 0, stream>>>(xnew, ln2_w, ln2_b, h2);

  gemm_fc1gelu<<<dim3(HID_ / 128, BN_ / 128), 256, 0, stream>>>(h2, wfc1, HID_, C_, fc1_b, act);

  gemm_fc2res<<<dim3(C_ / 128, BN_ / 128), 256, 0, stream>>>(act, wfc2, C_, HID_, fc2_b, xnew, out);
}

// Round 5
// 555.771 us; speedup vs baseline: 1.1986x; 1.1986x over previous
//
#include <hip/hip_runtime.h>

// Problem constants
#define B_   32
#define N_   512
#define C_   768
#define H_   12
#define D_   64
#define HID_ 3072
#define BN_  (B_*N_)      // 16384 rows

typedef unsigned short u16;
typedef __attribute__((ext_vector_type(8))) short  short8;   // 8 bf16 (4 VGPRs)
typedef __attribute__((ext_vector_type(4))) float  float4v;  // 4 fp32 acc

__device__ __forceinline__ u16 f32_to_bf16(float f) {
  unsigned u = __builtin_bit_cast(unsigned, f);
  u += 0x7fffu + ((u >> 16) & 1u);   // RNE
  return (u16)(u >> 16);
}

// async global->LDS, 16B per lane; lds base wave-uniform, lane i lands at base + i*16B
__device__ __forceinline__ void load_lds16(const u16* g, u16* l) {
  __builtin_amdgcn_global_load_lds(
      (const __attribute__((address_space(1))) unsigned int*)g,
      (__attribute__((address_space(3))) unsigned int*)l,
      16, 0, 0);
}

// ---------------- weight cast f32 -> bf16 ----------------
__global__ void cast_kernel(const float* __restrict__ src, u16* __restrict__ dst, int n) {
  int i = blockIdx.x * 256 + threadIdx.x;
  if (i < n) dst[i] = f32_to_bf16(src[i]);
}

// ---------------- LayerNorm (row = 768 fp32) -> bf16 ----------------
__global__ __launch_bounds__(256)
void ln_kernel(const float* __restrict__ x, const float* __restrict__ w,
               const float* __restrict__ bias, u16* __restrict__ out) {
  const int row = blockIdx.x;
  const int tid = threadIdx.x;
  const float* xr = x + (size_t)row * C_;
  float v0 = xr[tid], v1 = xr[tid + 256], v2 = xr[tid + 512];
  float s = v0 + v1 + v2;
  float q = v0*v0 + v1*v1 + v2*v2;
#pragma unroll
  for (int off = 1; off < 64; off <<= 1) { s += __shfl_xor(s, off); q += __shfl_xor(q, off); }
  __shared__ float red[8];
  int wave = tid >> 6, lane = tid & 63;
  if (lane == 0) { red[wave] = s; red[4 + wave] = q; }
  __syncthreads();
  s = red[0] + red[1] + red[2] + red[3];
  q = red[4] + red[5] + red[6] + red[7];
  float mean = s * (1.0f / C_);
  float var  = q * (1.0f / C_) - mean * mean;
  float rstd = rsqrtf(var + 1e-5f);
  u16* orow = out + (size_t)row * C_;
  orow[tid]       = f32_to_bf16((v0 - mean) * rstd * w[tid]       + bias[tid]);
  orow[tid + 256] = f32_to_bf16((v1 - mean) * rstd * w[tid + 256] + bias[tid + 256]);
  orow[tid + 512] = f32_to_bf16((v2 - mean) * rstd * w[tid + 512] + bias[tid + 512]);
}

// ------- V transpose: qkv unified [BN, 3C] V-cols -> Vt[B*H, D, N] --------------
// Block = (n-tile, bh). LDS 64x64 tile with 72-u16 row pitch (16B-aligned rows).
__global__ __launch_bounds__(256)
void transpose_v(const u16* __restrict__ qkv, u16* __restrict__ vt) {
  __shared__ alignas(16) u16 T[64 * 72];
  const int nt = blockIdx.x, bh = blockIdx.y;
  const int b = bh / H_, h = bh % H_;
  const int tid = threadIdx.x;
  const size_t rs3 = 3 * C_;
  // read: 64 n-rows x 64 d; thread: n-row tid>>2, d-chunk (tid&3)*16
  const int r = tid >> 2, dc = (tid & 3) * 16;
  const u16* src = qkv + (size_t)(b * N_ + nt * 64 + r) * rs3 + 2 * C_ + h * D_ + dc;
  short8 a0 = *(const short8*)src;
  short8 a1 = *(const short8*)(src + 8);
#pragma unroll
  for (int j = 0; j < 8; j++) T[(dc + j) * 72 + r] = (u16)a0[j];
#pragma unroll
  for (int j = 0; j < 8; j++) T[(dc + 8 + j) * 72 + r] = (u16)a1[j];
  __syncthreads();
  // write: 64 d-rows x 64 n; thread: d-row tid>>2, n-chunk (tid&3)*16
  const int d = tid >> 2, nc = (tid & 3) * 16;
  u16* dst = vt + ((size_t)(b * H_ + h) * D_ + d) * N_ + nt * 64 + nc;
  *(short8*)dst       = *(const short8*)&T[d * 72 + nc];
  *(short8*)(dst + 8) = *(const short8*)&T[d * 72 + nc + 8];
}

// ---------------- 128x128x(BK=64) bf16 NT GEMM: C[M,N] = A[M,K] * W[N,K]^T -------
// LDS XOR-swizzled: (row, 16B-group g) lives at row*128B + (g^(row&7))*16B.
// EPI 0: store bf16 (QKV)   EPI 1: gelu(y+bias)->bf16 (FC1)
// EPI 2: 2*(y+bias)->fp32 (proj)   EPI 3: y+bias+resid->fp32 (FC2)
template <int EPI>
__device__ __forceinline__ void gemm_core(const u16* __restrict__ A, const u16* __restrict__ W,
                                          int N, int K,
                                          const float* __restrict__ bias,
                                          const float* __restrict__ resid,
                                          u16* __restrict__ out_bf, float* __restrict__ out_f) {
  __shared__ alignas(16) u16 As[128 * 64];
  __shared__ alignas(16) u16 Ws[128 * 64];
  const int tid  = threadIdx.x;
  const int wave = tid >> 6;
  const int lane = tid & 63;
  const int quad = lane >> 4;
  const int l15  = lane & 15;

  // XCD-aware swizzle: row-major band per XCD for L2 A-strip sharing.
  const int nx    = gridDim.x;
  const int lin   = blockIdx.y * nx + blockIdx.x;
  const int total = nx * gridDim.y;
  const int v     = (lin & 7) * (total >> 3) + (lin >> 3);
  const int m0 = (v / nx) << 7;
  const int n0 = (v % nx) << 7;

  const int wm = (wave >> 1) * 64;
  const int wn = (wave & 1) * 64;

  float4v acc[4][4];
#pragma unroll
  for (int i = 0; i < 4; i++)
#pragma unroll
    for (int j = 0; j < 4; j++) acc[i][j] = (float4v){0.f, 0.f, 0.f, 0.f};

  const int c0   = wave * 4;
  const int srow = lane >> 3;
  const int gcol = ((lane & 7) ^ srow) * 8;
  const u16* Ag[4];
  const u16* Wg[4];
#pragma unroll
  for (int j = 0; j < 4; j++) {
    const int row = (c0 + j) * 8 + srow;
    Ag[j] = A + (size_t)(m0 + row) * K + gcol;
    Wg[j] = W + (size_t)(n0 + row) * K + gcol;
  }

  for (int k0 = 0; k0 < K; k0 += 64) {
    __syncthreads();
#pragma unroll
    for (int j = 0; j < 4; j++) load_lds16(Ag[j] + k0, &As[(c0 + j) * 512]);
#pragma unroll
    for (int j = 0; j < 4; j++) load_lds16(Wg[j] + k0, &Ws[(c0 + j) * 512]);
    __syncthreads();

    short8 af[4][2], bf[4][2];
#pragma unroll
    for (int mi = 0; mi < 4; mi++)
#pragma unroll
      for (int ks = 0; ks < 2; ks++) {
        const int swz = ((ks * 4 + quad) ^ (l15 & 7)) * 8;
        af[mi][ks] = *(const short8*)&As[(wm + mi * 16 + l15) * 64 + swz];
        bf[mi][ks] = *(const short8*)&Ws[(wn + mi * 16 + l15) * 64 + swz];
      }
#pragma unroll
    for (int ks = 0; ks < 2; ks++)
#pragma unroll
      for (int mi = 0; mi < 4; mi++)
#pragma unroll
        for (int ni = 0; ni < 4; ni++)
          acc[mi][ni] = __builtin_amdgcn_mfma_f32_16x16x32_bf16(af[mi][ks], bf[ni][ks], acc[mi][ni], 0, 0, 0);
  }

#pragma unroll
  for (int mi = 0; mi < 4; mi++) {
#pragma unroll
    for (int r = 0; r < 4; r++) {
      const int row = m0 + wm + mi * 16 + quad * 4 + r;   // C/D: row = quad*4+reg (m89)
#pragma unroll
      for (int ni = 0; ni < 4; ni++) {
        const int col = n0 + wn + ni * 16 + l15;          // C/D: col = lane&15
        float v2 = acc[mi][ni][r];
        if (EPI == 0) {
          out_bf[(size_t)row * N + col] = f32_to_bf16(v2);
        } else if (EPI == 1) {
          v2 += bias[col];
          v2 = 0.5f * v2 * (1.0f + erff(v2 * 0.70710678118654752f));  // exact GELU
          out_bf[(size_t)row * N + col] = f32_to_bf16(v2);
        } else if (EPI == 2) {
          out_f[(size_t)row * N + col] = 2.0f * (v2 + bias[col]);     // x = o + o quirk
        } else {
          out_f[(size_t)row * N + col] = v2 + bias[col] + resid[(size_t)row * N + col];
        }
      }
    }
  }
}

__global__ __launch_bounds__(256, 3)
void gemm_qkv(const u16* __restrict__ A, const u16* __restrict__ W, int N, int K,
              u16* __restrict__ out_bf) {
  gemm_core<0>(A, W, N, K, nullptr, nullptr, out_bf, nullptr);
}
__global__ __launch_bounds__(256, 3)
void gemm_proj2x(const u16* __restrict__ A, const u16* __restrict__ W, int N, int K,
                 const float* __restrict__ bias, float* __restrict__ out_f) {
  gemm_core<2>(A, W, N, K, bias, nullptr, nullptr, out_f);
}
__global__ __launch_bounds__(256, 3)
void gemm_fc1gelu(const u16* __restrict__ A, const u16* __restrict__ W, int N, int K,
                  const float* __restrict__ bias, u16* __restrict__ out_bf) {
  gemm_core<1>(A, W, N, K, bias, nullptr, out_bf, nullptr);
}
__global__ __launch_bounds__(256, 3)
void gemm_fc2res(const u16* __restrict__ A, const u16* __restrict__ W, int N, int K,
                 const float* __restrict__ bias, const float* __restrict__ resid,
                 float* __restrict__ out_f) {
  gemm_core<3>(A, W, N, K, bias, resid, nullptr, out_f);
}

// ---------------- flash attention v3 ---------------------------------------------
// Block = 128 queries of one (b,h); 4 waves x 2 strips of 16 q.  K tile (64x64)
// and V tile (64 d x 64 keys, from Vt) staged in LDS via global_load_lds with the
// XOR swizzle (conflict-free b128 reads).  1D grid lin = qt*384 + bh so all blocks
// of one (b,h) share an XCD (384 % 8 == 0).  P strips are per-wave (no barriers).
__global__ __launch_bounds__(256)
void attn_kernel(const u16* __restrict__ qkv, const u16* __restrict__ vt,
                 u16* __restrict__ o) {
  __shared__ alignas(16) u16 Ks[64 * 64];
  __shared__ alignas(16) u16 Vs[64 * 64];
  __shared__ alignas(16) u16 Ps[8][16 * 64];
  const int tid  = threadIdx.x;
  const int wave = tid >> 6, lane = tid & 63;
  const int quad = lane >> 4, l15 = lane & 15;
  const int lin = blockIdx.x;
  const int bh = lin % 384, qt = lin / 384;
  const int b = bh / H_, h = bh % H_;
  const size_t rs3 = 3 * C_;

  // Q fragments from global (A-layout: m=lane&15, k=quad*8+j), 2 strips
  short8 qf[2][2];
#pragma unroll
  for (int st = 0; st < 2; st++) {
    const int qrow = b * N_ + qt * 128 + st * 64 + wave * 16 + l15;
    const u16* qp = qkv + (size_t)qrow * rs3 + h * D_ + quad * 8;
    qf[st][0] = *(const short8*)qp;
    qf[st][1] = *(const short8*)(qp + 32);
  }

  // staging sources (8 chunks of 8 rows; wave stages chunks 2w, 2w+1)
  const int srow = lane >> 3;                       // row within chunk
  const int gcol = ((lane & 7) ^ srow) * 8;         // XOR-swizzled 16B group
  const int ch0 = wave * 2, ch1 = wave * 2 + 1;
  const u16* kg0 = qkv + (size_t)(b * N_ + ch0 * 8 + srow) * rs3 + C_ + h * D_ + gcol;
  const u16* kg1 = qkv + (size_t)(b * N_ + ch1 * 8 + srow) * rs3 + C_ + h * D_ + gcol;
  const u16* vg0 = vt + ((size_t)bh * D_ + ch0 * 8 + srow) * N_ + gcol;
  const u16* vg1 = vt + ((size_t)bh * D_ + ch1 * 8 + srow) * N_ + gcol;

  float m[2][4], l[2][4];
  float4v oacc[2][4];
#pragma unroll
  for (int st = 0; st < 2; st++)
#pragma unroll
    for (int r = 0; r < 4; r++) { m[st][r] = -1e30f; l[st][r] = 0.f; }
#pragma unroll
  for (int st = 0; st < 2; st++)
#pragma unroll
    for (int ni = 0; ni < 4; ni++) oacc[st][ni] = (float4v){0.f, 0.f, 0.f, 0.f};

  for (int kt = 0; kt < 8; ++kt) {
    __syncthreads();
    load_lds16(kg0 + (size_t)(kt * 64) * rs3, &Ks[ch0 * 512]);
    load_lds16(kg1 + (size_t)(kt * 64) * rs3, &Ks[ch1 * 512]);
    load_lds16(vg0 + kt * 64, &Vs[ch0 * 512]);
    load_lds16(vg1 + kt * 64, &Vs[ch1 * 512]);
    __syncthreads();

    // K fragments (B[n=key][k=d]) shared by both strips
    short8 kf[4][2];
#pragma unroll
    for (int ni = 0; ni < 4; ni++)
#pragma unroll
      for (int ks = 0; ks < 2; ks++)
        kf[ni][ks] = *(const short8*)&Ks[(ni * 16 + l15) * 64 + ((ks * 4 + quad) ^ (l15 & 7)) * 8];

#pragma unroll
    for (int st = 0; st < 2; st++) {
      u16* myPs = Ps[wave * 2 + st];
      float4v s[4];
#pragma unroll
      for (int ni = 0; ni < 4; ni++) {
        s[ni] = (float4v){0.f, 0.f, 0.f, 0.f};
        s[ni] = __builtin_amdgcn_mfma_f32_16x16x32_bf16(qf[st][0], kf[ni][0], s[ni], 0, 0, 0);
        s[ni] = __builtin_amdgcn_mfma_f32_16x16x32_bf16(qf[st][1], kf[ni][1], s[ni], 0, 0, 0);
      }

      float mt[4];
#pragma unroll
      for (int r = 0; r < 4; r++)
        mt[r] = 0.125f * fmaxf(fmaxf(s[0][r], s[1][r]), fmaxf(s[2][r], s[3][r]));
#pragma unroll
      for (int off = 1; off < 16; off <<= 1)
#pragma unroll
        for (int r = 0; r < 4; r++) mt[r] = fmaxf(mt[r], __shfl_xor(mt[r], off));

      float alpha[4], mnew[4], rsum[4];
#pragma unroll
      for (int r = 0; r < 4; r++) {
        mnew[r] = fmaxf(m[st][r], mt[r]);
        alpha[r] = __expf(m[st][r] - mnew[r]);
        rsum[r] = 0.f;
      }
      // write P swizzled: row*64 + ((key>>3)^(row&7))*8 + (key&7)
#pragma unroll
      for (int ni = 0; ni < 4; ni++)
#pragma unroll
        for (int r = 0; r < 4; r++) {
          float p = __expf(s[ni][r] * 0.125f - mnew[r]);
          rsum[r] += p;
          const int prow = quad * 4 + r;
          const int g = (ni * 2 + (l15 >> 3)) ^ (prow & 7);
          myPs[prow * 64 + g * 8 + (l15 & 7)] = f32_to_bf16(p);
        }
#pragma unroll
      for (int off = 1; off < 16; off <<= 1)
#pragma unroll
        for (int r = 0; r < 4; r++) rsum[r] += __shfl_xor(rsum[r], off);
#pragma unroll
      for (int r = 0; r < 4; r++) { l[st][r] = l[st][r] * alpha[r] + rsum[r]; m[st][r] = mnew[r]; }
#pragma unroll
      for (int ni = 0; ni < 4; ni++)
#pragma unroll
        for (int r = 0; r < 4; r++) oacc[st][ni][r] *= alpha[r];

      // O += P V (pf: A[m=q][k=key]; vf: B[n=d][k=key] from Vs, swizzled)
#pragma unroll
      for (int ks = 0; ks < 2; ks++) {
        const int g = (ks * 4 + quad) ^ (l15 & 7);
        short8 pf = *(const short8*)&myPs[l15 * 64 + g * 8];
#pragma unroll
        for (int ni = 0; ni < 4; ni++) {
          short8 vf = *(const short8*)&Vs[(ni * 16 + l15) * 64 + ((ks * 4 + quad) ^ (l15 & 7)) * 8];
          oacc[st][ni] = __builtin_amdgcn_mfma_f32_16x16x32_bf16(pf, vf, oacc[st][ni], 0, 0, 0);
        }
      }
    }
  }

#pragma unroll
  for (int st = 0; st < 2; st++) {
    float inv[4];
#pragma unroll
    for (int r = 0; r < 4; r++) inv[r] = 1.0f / l[st][r];
#pragma unroll
    for (int ni = 0; ni < 4; ni++)
#pragma unroll
      for (int r = 0; r < 4; r++) {
        int row = b * N_ + qt * 128 + st * 64 + wave * 16 + quad * 4 + r;
        int col = h * D_ + ni * 16 + l15;
        o[(size_t)row * C_ + col] = f32_to_bf16(oacc[st][ni][r] * inv[r]);
      }
  }
}

// ---------------- launch ----------------
extern "C" void kernel_launch(void* const* d_in, const int* in_sizes, int n_in,
                              void* d_out, int out_size, void* d_ws, size_t ws_size,
                              hipStream_t stream) {
  const float* x      = (const float*)d_in[0];
  const float* ln1_w  = (const float*)d_in[1];
  const float* ln1_b  = (const float*)d_in[2];
  const float* qkv_w  = (const float*)d_in[3];
  const float* proj_w = (const float*)d_in[4];
  const float* proj_b = (const float*)d_in[5];
  const float* ln2_w  = (const float*)d_in[6];
  const float* ln2_b  = (const float*)d_in[7];
  const float* fc1_w  = (const float*)d_in[8];
  const float* fc1_b  = (const float*)d_in[9];
  const float* fc2_w  = (const float*)d_in[10];
  const float* fc2_b  = (const float*)d_in[11];
  float* out = (float*)d_out;

  char* ws = (char*)d_ws;
  size_t off = 0;
  auto alloc = [&](size_t bytes) { void* p = ws + off; off += (bytes + 255) & ~255ull; return p; };
  u16* wqkv  = (u16*)alloc((size_t)3 * C_ * C_ * 2);
  u16* wproj = (u16*)alloc((size_t)C_ * C_ * 2);
  u16* wfc1  = (u16*)alloc((size_t)HID_ * C_ * 2);
  u16* wfc2  = (u16*)alloc((size_t)C_ * HID_ * 2);
  u16* regionA = (u16*)alloc((size_t)BN_ * HID_ * 2);  // h | qkv, later o, later act
  float* xnew  = (float*)alloc((size_t)BN_ * C_ * 4);
  u16* h2      = (u16*)alloc((size_t)BN_ * C_ * 2);

  u16* hbuf = regionA;                        // [BN, C]   (dead after QKV)
  u16* qkvb = regionA + (size_t)BN_ * C_;     // [BN, 3C]  (dead after attn)
  u16* obuf = regionA;                        // [BN, C]   overwrites hbuf
  u16* act  = regionA;                        // [BN, HID] overwrites qkv+o
  u16* vtbuf = (u16*)xnew;                    // [B*H, D, N] aliases xnew (dead before proj writes)

  cast_kernel<<<dim3(3 * C_ * C_ / 256), 256, 0, stream>>>(qkv_w, wqkv, 3 * C_ * C_);
  cast_kernel<<<dim3(C_ * C_ / 256), 256, 0, stream>>>(proj_w, wproj, C_ * C_);
  cast_kernel<<<dim3(HID_ * C_ / 256), 256, 0, stream>>>(fc1_w, wfc1, HID_ * C_);
  cast_kernel<<<dim3(HID_ * C_ / 256), 256, 0, stream>>>(fc2_w, wfc2, C_ * HID_);

  ln_kernel<<<dim3(BN_), 256, 0, stream>>>(x, ln1_w, ln1_b, hbuf);

  gemm_qkv<<<dim3(3 * C_ / 128, BN_ / 128), 256, 0, stream>>>(hbuf, wqkv, 3 * C_, C_, qkvb);

  transpose_v<<<dim3(N_ / 64, B_ * H_), 256, 0, stream>>>(qkvb, vtbuf);

  attn_kernel<<<dim3((N_ / 128) * B_ * H_), 256, 0, stream>>>(qkvb, vtbuf, obuf);

  gemm_proj2x<<<dim3(C_ / 128, BN_ / 128), 256, 0, stream>>>(obuf, wproj, C_, C_, proj_b, xnew);

  ln_kernel<<<dim3(BN_), 256, 0, stream>>>(xnew, ln2_w, ln2_b, h2);

  gemm_fc1gelu<<<dim3(HID_ / 128, BN_ / 128), 256, 0, stream>>>(h2, wfc1, HID_, C_, fc1_b, act);

  gemm_fc2res<<<dim3(C_ / 128, BN_ / 128), 256, 0, stream>>>(act, wfc2, C_, HID_, fc2_b, xnew, out);
}